// Round 5
// baseline (1104.447 us; speedup 1.0000x reference)
//
#include <hip/hip_runtime.h>

// Problem constants: B=16, T=4096, D=256, K=1024
#define N_TOK 65536
#define DIM   256
#define KCODE 1024

#define NTHREADS 512    // 8 waves: 2 (token dim) x 4 (code dim)
#define BM 256          // tokens per block
#define BN 256          // codes per block
#define NCHUNK 4        // code chunks (1024/256)
#define NKT 12          // K-tiles of 64: 3 segments x 4

// fp32 gap below which the top-2 go to fp64 refinement (bf16x3 dot err ~1e-2 bound)
#define REFINE_EPS 0.125f
// fp64 gap below which the reference's fp32 pipeline likely collapsed the two
// distances onto the same fp32 grid point -> first-occurrence -> LOWER index.
#define TIE_THETA 1.0e-4

// ws layout (floats):
//   [0]                    loss accum
//   [16 .. 16+1024)        c_sq (numpy-pairwise-exact)
//   [2048 .. +65536)       idx (int) final argmin
//   [67584 .. +8*4*65536)  pairs region (float4, chunk-major: pairs[c*N_TOK+t])
//   [then]                 cb packed tile-major bf16 hi/lo (1 MB)
#define WS_CSQ_OFF   16
#define WS_IDX_OFF   2048
#define WS_PAIRS_OFF (WS_IDX_OFF + N_TOK)
#define WS_CBPK_OFF  (WS_PAIRS_OFF + N_TOK * 8 * 4)

typedef float f32x4  __attribute__((ext_vector_type(4)));
typedef short bf16x8 __attribute__((ext_vector_type(8)));
typedef short s16x8  __attribute__((ext_vector_type(8)));

__global__ void zero_loss_kernel(float* ws) {
    if (threadIdx.x == 0) ws[0] = 0.0f;
}

// numpy-pairwise-exact row sum-of-squares for [rows, 256] fp32 (codebook).
__global__ void rowsq_np_kernel(const float* __restrict__ m,
                                float* __restrict__ out, int rows) {
#pragma clang fp contract(off)
    int row = blockIdx.x * 16 + (threadIdx.x >> 4);
    int l   = threadIdx.x & 15;
    if (row >= rows) return;
    int h = l >> 3;
    int j = l & 7;
    const float* p = m + (size_t)row * DIM + h * 128 + j;
    float v = p[0];
    float r = v * v;
#pragma unroll
    for (int i = 1; i < 16; ++i) {
        float w  = p[i * 8];
        float w2 = w * w;
        r = r + w2;
    }
    float t = r + __shfl_xor(r, 1);
    t = t + __shfl_xor(t, 2);
    t = t + __shfl_xor(t, 4);
    t = t + __shfl_xor(t, 8);
    if (l == 0) out[row] = t;
}

// Insert (d, idx) into a sorted top-2 with lower-index tie-break.
__device__ __forceinline__ void ins2(float d, int idx,
                                     float& d1, int& i1, float& d2, int& i2) {
    if (d < d1 || (d == d1 && idx < i1)) {
        d2 = d1; i2 = i1; d1 = d; i1 = idx;
    } else if ((d < d2 || (d == d2 && idx < i2)) && idx != i1) {
        d2 = d; i2 = idx;
    }
}

// RNE fp32 -> bf16 split: v = hi + lo with lo capturing the residual.
__device__ __forceinline__ void f2bf_split(float v, short& hi, short& lo) {
    unsigned u = __float_as_uint(v);
    unsigned r = (u + 0x7fffu + ((u >> 16) & 1u)) >> 16;
    hi = (short)r;
    float hf = __uint_as_float(r << 16);
    float lf = v - hf;
    unsigned u2 = __float_as_uint(lf);
    unsigned r2 = (u2 + 0x7fffu + ((u2 >> 16) & 1u)) >> 16;
    lo = (short)r2;
}

// R5 pack: chunk = (group*8 + part*4 + kc), each chunk 256 rows x 64 k-elems
// bf16 = 32 KB contiguous (group = 256 rows; part: 0=hi, 4-offset=lo; kc =
// 64-k tile 0..3). Within a row, octet o (8 shorts, k = kc*64 + o*8) is
// stored at slot (o ^ (r&7)) — the LDS bank swizzle baked into global
// layout so global_load_lds stages linearly on BOTH sides (rule #21) and
// ds_read applies the same XOR. Rows stride 128 B, so without the XOR a
// fragment read (16 rows, fixed slot) is a 16-way bank conflict; with it,
// 2-way (free, m136).
__global__ void pack_tiles_kernel(const float* __restrict__ src,
                                  unsigned short* __restrict__ dst,
                                  int total) {       // total = rows * 32
    int tid = blockIdx.x * blockDim.x + threadIdx.x;
    if (tid >= total) return;
    int oc  = tid & 31;        // octet within row, 0..31
    int row = tid >> 5;
    int g   = row >> 8;        // 256-row group
    int r   = row & 255;
    int kc  = oc >> 3;         // 64-k tile, 0..3
    int o   = oc & 7;          // octet within tile

    const float4* xr = reinterpret_cast<const float4*>(
        src + (size_t)row * DIM + oc * 8);
    float4 v0 = xr[0];
    float4 v1 = xr[1];

    float f[8] = {v0.x, v0.y, v0.z, v0.w, v1.x, v1.y, v1.z, v1.w};
    s16x8 hv, lv;
#pragma unroll
    for (int i = 0; i < 8; ++i) {
        short h, l;
        f2bf_split(f[i], h, l);
        hv[i] = h; lv[i] = l;
    }
    int slot = o ^ (r & 7);
    size_t bhi = ((size_t)(g * 8 + kc)     * 256 + r) * 64 + slot * 8;
    size_t blo = ((size_t)(g * 8 + 4 + kc) * 256 + r) * 64 + slot * 8;
    *reinterpret_cast<s16x8*>(dst + bhi) = hv;
    *reinterpret_cast<s16x8*>(dst + blo) = lv;
}

// Async global -> LDS, 16 B per lane; LDS dest = uniform base + lane*16.
__device__ __forceinline__ void gload_lds16(const unsigned short* g, unsigned short* lds) {
    __builtin_amdgcn_global_load_lds(
        (const __attribute__((address_space(1))) unsigned int*)g,
        (__attribute__((address_space(3))) unsigned int*)lds, 16, 0, 0);
}

// MFMA distance + top-2. dist' = c_sq - 2*(x.c); ||x||^2 dropped (cancels).
// dot = hi*hi + hi*lo + lo*hi as one K=768 concat-GEMM over 3 segments.
//
// R5: counted-vmcnt 256x256 schedule (guide T2+T3+T4+T5). R0-R4 proved the
// 2-phase stage->drain->compute lockstep costs ~90% regardless of barriers/
// LDS/occupancy (m233's finding). This structure:
//  - raw s_barrier + inline-asm s_waitcnt vmcnt(8): each wave issues exactly
//    8 global_load_lds per K-tile, so vmcnt(8) = "my tile landed, next tile
//    still in flight". vmcnt NEVER drains to 0 in the loop (T4).
//  - 2 x 64 KB LDS double-buffer (128 KB dynamic), 12 K-tiles of 64.
//  - bank swizzle baked into pack layout (T2); setprio around MFMA (T5).
//  - per-acc accumulation order: seg-major, kc ascending, t0 then t1 —
//    identical to R2/R4 -> bit-exact.
#define LDFRAG(ptr) (*reinterpret_cast<const bf16x8*>(ptr))
#define QUAD(pb, h, bft, st)                                                 \
    do {                                                                     \
        bf16x8 af_[4];                                                       \
        _Pragma("unroll")                                                    \
        for (int j_ = 0; j_ < 4; ++j_)                                       \
            af_[j_] = LDFRAG((pb) + baseA + ((h) * 4 + j_) * 1024 + (st));   \
        __builtin_amdgcn_s_setprio(1);                                       \
        _Pragma("unroll")                                                    \
        for (int j_ = 0; j_ < 4; ++j_) {                                     \
            _Pragma("unroll")                                                \
            for (int n_ = 0; n_ < 4; ++n_)                                   \
                acc[(h) * 4 + j_][n_] =                                      \
                    __builtin_amdgcn_mfma_f32_16x16x32_bf16(                 \
                        af_[j_], bft[n_], acc[(h) * 4 + j_][n_], 0, 0, 0);   \
        }                                                                    \
        __builtin_amdgcn_s_setprio(0);                                       \
    } while (0)

#define TILE_BODY(pb)                                                        \
    do {                                                                     \
        bf16x8 bf0_[4], bf1_[4];                                             \
        _Pragma("unroll")                                                    \
        for (int n_ = 0; n_ < 4; ++n_)                                       \
            bf0_[n_] = LDFRAG((pb) + baseB + n_ * 1024 + s0);                \
        _Pragma("unroll")                                                    \
        for (int n_ = 0; n_ < 4; ++n_)                                       \
            bf1_[n_] = LDFRAG((pb) + baseB + n_ * 1024 + s1);                \
        QUAD(pb, 0, bf0_, s0);                                               \
        QUAD(pb, 0, bf1_, s1);                                               \
        QUAD(pb, 1, bf0_, s0);                                               \
        QUAD(pb, 1, bf1_, s1);                                               \
    } while (0)

__launch_bounds__(NTHREADS, 1)
__global__ void vq_main_kernel(const unsigned short* __restrict__ xpk,
                               const unsigned short* __restrict__ cbpk,
                               const float* __restrict__ csq,
                               float4* __restrict__ pairs) {
    extern __shared__ unsigned short shmem[];   // 2 x (A 16384 | B 16384) shorts

    const int tid  = threadIdx.x;
    const int w    = tid >> 6;       // wave 0..7
    const int wy   = w >> 2;         // wave row (token dim), 0..1
    const int wx   = w & 3;          // wave col (code dim), 0..3
    const int lane = tid & 63;
    const int lm   = lane & 15;
    const int q    = lane >> 4;

    // XCD swizzle (bijective, 1024 blocks): each XCD gets 32 consecutive
    // token groups x all 4 code chunks -> A slabs L2-shared.
    const int bx    = blockIdx.x;
    const int swz   = (bx & 7) * 128 + (bx >> 3);
    const int grp   = swz >> 2;      // token group 0..255
    const int nb    = swz & 3;       // code chunk 0..3
    const int tok0  = grp * BM;
    const int code0 = nb * BN;

    float cs_reg[4];
#pragma unroll
    for (int ni = 0; ni < 4; ++ni)
        cs_reg[ni] = csq[code0 + wx * 64 + ni * 16 + lm];

    f32x4 acc[8][4];
#pragma unroll
    for (int mi = 0; mi < 8; ++mi)
#pragma unroll
        for (int ni = 0; ni < 4; ++ni)
            acc[mi][ni] = (f32x4){0.f, 0.f, 0.f, 0.f};

    // LDS read geometry. Row r stride = 64 shorts. Fragment octet for K-half
    // t is (t*4+q) at swizzled slot (t*4+q)^(r&7); since 16|row-offsets,
    // r&7 == lm&7 for every fragment -> slot is fragment-invariant.
    const int s0    = ((q)     ^ (lm & 7)) * 8;   // t=0 slot (shorts)
    const int s1    = ((4 + q) ^ (lm & 7)) * 8;   // t=1 slot
    const int baseA = (wy * 128 + lm) * 64;
    const int baseB = 16384 + (wx * 64 + lm) * 64;

    // K-tile kt (0..11): kc = kt&3. A part: hi,hi,lo ; B part: hi,lo,hi.
    auto stage = [&](int p, int kt) {
        const int cidA = grp * 8 + ((kt >= 8) ? 4 : 0) + (kt & 3);
        const int cidB = nb * 8 + ((kt >= 4 && kt < 8) ? 4 : 0) + (kt & 3);
        const unsigned short* ga = xpk + ((size_t)cidA << 14) + tid * 8;
        const unsigned short* gb = cbpk + ((size_t)cidB << 14) + tid * 8;
        unsigned short* la = &shmem[p * 32768 + tid * 8];
        unsigned short* lb = &shmem[p * 32768 + 16384 + tid * 8];
#pragma unroll
        for (int i = 0; i < 4; ++i) gload_lds16(ga + i * 4096, la + i * 4096);
#pragma unroll
        for (int i = 0; i < 4; ++i) gload_lds16(gb + i * 4096, lb + i * 4096);
    };

    // Prologue: two tiles in flight (16 outstanding loads per wave).
    stage(0, 0);
    stage(1, 1);

    int p = 0;
#pragma unroll 1
    for (int kt = 0; kt < NKT - 1; ++kt) {
        // My oldest 8 loads (= tile kt) landed; tile kt+1's 8 stay in flight.
        asm volatile("s_waitcnt vmcnt(8)" ::: "memory");
        __builtin_amdgcn_s_barrier();          // all waves' tile-kt landed
        __builtin_amdgcn_sched_barrier(0);
        const unsigned short* pb = &shmem[p * 32768];
        TILE_BODY(pb);
        __builtin_amdgcn_sched_barrier(0);
        __builtin_amdgcn_s_barrier();          // all waves done reading buf p
        if (kt < NKT - 2) stage(p, kt + 2);    // refill just-freed buffer
        p ^= 1;
    }
    // Peeled last tile: only now drain to 0.
    asm volatile("s_waitcnt vmcnt(0)" ::: "memory");
    __builtin_amdgcn_s_barrier();
    __builtin_amdgcn_sched_barrier(0);
    {
        const unsigned short* pb = &shmem[p * 32768];
        TILE_BODY(pb);
    }

    // buf0 (bytes [0,64K)) last read at kt=10 whose trailing barrier all
    // waves passed -> safe to overlay pairs_sh there while others finish
    // kt=11 (they read buf1, bytes [64K,128K)).
    float4 (*pairs_sh)[4] = reinterpret_cast<float4(*)[4]>(shmem);

    // Extraction: C/D layout row=(q*4+reg), col=lm per 16x16 tile (verified R6).
#pragma unroll
    for (int mi = 0; mi < 8; ++mi) {
#pragma unroll
        for (int rr = 0; rr < 4; ++rr) {
            int row_local = wy * 128 + mi * 16 + q * 4 + rr;
            float l1 = 3.4e38f, l2 = 3.4e38f;
            int   j1 = 0x7fffffff, j2 = 0x7fffffff;
#pragma unroll
            for (int ni = 0; ni < 4; ++ni) {
                float d = cs_reg[ni] - 2.0f * acc[mi][ni][rr];
                ins2(d, code0 + wx * 64 + ni * 16 + lm, l1, j1, l2, j2);
            }
#pragma unroll
            for (int m = 1; m < 16; m <<= 1) {
                float o1 = __shfl_xor(l1, m);
                int   p1 = __shfl_xor(j1, m);
                float o2 = __shfl_xor(l2, m);
                int   p2 = __shfl_xor(j2, m);
                ins2(o1, p1, l1, j1, l2, j2);
                ins2(o2, p2, l1, j1, l2, j2);
            }
            if (lm == 0) {
                float4 pr;
                pr.x = l1; pr.y = l2;
                pr.z = __int_as_float(j1); pr.w = __int_as_float(j2);
                pairs_sh[row_local][wx] = pr;
            }
        }
    }
    __syncthreads();
    if (tid < BM) {
        float4 p0 = pairs_sh[tid][0];
        float d1 = p0.x, d2 = p0.y;
        int   i1 = __float_as_int(p0.z), i2 = __float_as_int(p0.w);
#pragma unroll
        for (int c = 1; c < 4; ++c) {
            float4 pc = pairs_sh[tid][c];
            ins2(pc.x, __float_as_int(pc.z), d1, i1, d2, i2);
            ins2(pc.y, __float_as_int(pc.w), d1, i1, d2, i2);
        }
        float4 pr;
        pr.x = d1; pr.y = d2;
        pr.z = __int_as_float(i1); pr.w = __int_as_float(i2);
        // chunk-major: contiguous 16B stores across tid
        pairs[(size_t)nb * N_TOK + tok0 + tid] = pr;
    }
}
#undef TILE_BODY
#undef QUAD
#undef LDFRAG

// Merge 4 chunk top-2 pairs (ascending code order; union top-2 of exact
// partition top-2s is partition-invariant), then fp64 refine near-ties with
// the collapse-tolerant tie-break (proven R4-R6).
__global__ void merge_refine_kernel(const float* __restrict__ x,
                                    const float* __restrict__ cb,
                                    const float4* __restrict__ pairs,
                                    int* __restrict__ idx_out) {
    int t = blockIdx.x * 256 + threadIdx.x;
    if (t >= N_TOK) return;
    float4 p0 = pairs[t];
    float d1 = p0.x, d2 = p0.y;
    int   i1 = __float_as_int(p0.z), i2 = __float_as_int(p0.w);
#pragma unroll
    for (int c = 1; c < NCHUNK; ++c) {
        float4 p = pairs[(size_t)c * N_TOK + t];
        ins2(p.x, __float_as_int(p.z), d1, i1, d2, i2);
        ins2(p.y, __float_as_int(p.w), d1, i1, d2, i2);
    }

    int pick = i1;
    if (d2 - d1 < REFINE_EPS) {
        const float* xr = x + (size_t)t * DIM;
        const float* c1 = cb + (size_t)i1 * DIM;
        const float* c2 = cb + (size_t)i2 * DIM;
        double sA = 0.0, dA = 0.0, sB = 0.0, dB = 0.0;
        for (int k = 0; k < DIM; ++k) {
            double xv = (double)xr[k];
            double a  = (double)c1[k];
            double b  = (double)c2[k];
            sA += a * a; dA += xv * a;
            sB += b * b; dB += xv * b;
        }
        double DA  = sA - 2.0 * dA;
        double DB  = sB - 2.0 * dB;
        double gap = DB - DA;
        if (gap > TIE_THETA)       pick = i1;
        else if (gap < -TIE_THETA) pick = i2;
        else                       pick = (i1 < i2) ? i1 : i2;
    }
    idx_out[t] = pick;
}

// Output: quantized rows (exact ref math: x + (q - x)), indices as float,
// commitment-loss partial sums. Overwrites the x-packed scratch in out_q.
#define OTM 128
__launch_bounds__(256)
__global__ void output_kernel(const float* __restrict__ x,
                              const float* __restrict__ cb,
                              const int* __restrict__ idx,
                              float* __restrict__ out_q,
                              float* __restrict__ out_idx,
                              float* __restrict__ loss_ws) {
    __shared__ int   sh_idx[OTM];
    __shared__ float wsum[4];
    const int tid  = threadIdx.x;
    const int tok0 = blockIdx.x * OTM;

    if (tid < OTM) sh_idx[tid] = idx[tok0 + tid];
    __syncthreads();

    float lsum = 0.0f;
    for (int t = 0; t < OTM; ++t) {
        int code = sh_idx[t];
        float qv = cb[(size_t)code * DIM + tid];
        float xv = x[(size_t)(tok0 + t) * DIM + tid];
        out_q[(size_t)(tok0 + t) * DIM + tid] = xv + (qv - xv);
        float df = xv - qv;
        lsum = fmaf(df, df, lsum);
    }
    if (tid < OTM) out_idx[tok0 + tid] = (float)sh_idx[tid];

#pragma unroll
    for (int off = 1; off < 64; off <<= 1) lsum += __shfl_xor(lsum, off);
    if ((tid & 63) == 0) wsum[tid >> 6] = lsum;
    __syncthreads();
    if (tid == 0) atomicAdd(loss_ws, (wsum[0] + wsum[1]) + (wsum[2] + wsum[3]));
}

__global__ void finalize_kernel(const float* ws, float* out_loss) {
    if (threadIdx.x == 0) out_loss[0] = ws[0] * (1.0f / 16777216.0f); // COMMITMENT * mean
}

extern "C" void kernel_launch(void* const* d_in, const int* in_sizes, int n_in,
                              void* d_out, int out_size, void* d_ws, size_t ws_size,
                              hipStream_t stream) {
    const float* x  = (const float*)d_in[0];   // [16,4096,256] fp32
    const float* cb = (const float*)d_in[1];   // [1024,256] fp32

    float* out      = (float*)d_out;
    float* out_q    = out;
    float* out_idx  = out + (size_t)N_TOK * DIM;
    float* out_loss = out_idx + N_TOK;

    float*  ws    = (float*)d_ws;
    float*  csq   = ws + WS_CSQ_OFF;
    int*    idx   = (int*)(ws + WS_IDX_OFF);
    float4* pairs = (float4*)(ws + WS_PAIRS_OFF);
    unsigned short* cbpk = (unsigned short*)(ws + WS_CBPK_OFF);
    // x packed bf16 hi/lo lives in the out_q region (64 MB, overwritten later)
    unsigned short* xpk  = (unsigned short*)out_q;

    zero_loss_kernel<<<1, 64, 0, stream>>>(ws);
    rowsq_np_kernel<<<KCODE / 16, 256, 0, stream>>>(cb, csq, KCODE);
    // x: 65536 rows * 32 threads/row; cb: 1024 rows * 32 threads/row
    pack_tiles_kernel<<<(N_TOK * 32) / 256, 256, 0, stream>>>(x, xpk, N_TOK * 32);
    pack_tiles_kernel<<<(KCODE * 32) / 256, 256, 0, stream>>>(cb, cbpk, KCODE * 32);
    // 256 token groups x 4 code chunks; 512 threads; 128 KB dynamic LDS
    vq_main_kernel<<<(N_TOK / BM) * NCHUNK, NTHREADS, 131072, stream>>>(
        xpk, cbpk, csq, pairs);
    merge_refine_kernel<<<N_TOK / 256, 256, 0, stream>>>(x, cb, pairs, idx);
    output_kernel<<<N_TOK / OTM, 256, 0, stream>>>(x, cb, idx, out_q, out_idx, ws);
    finalize_kernel<<<1, 64, 0, stream>>>(ws, out_loss);
}

// Round 6
// 816.372 us; speedup vs baseline: 1.3529x; 1.3529x over previous
//
#include <hip/hip_runtime.h>

// Problem constants: B=16, T=4096, D=256, K=1024
#define N_TOK 65536
#define DIM   256
#define KCODE 1024

#define NTHREADS 256
#define TM 128          // tokens per block
#define TN 128          // codes per block
#define BK 32           // bf16 k-elems per stage
#define NCHUNK 8        // code chunks (1024/128)
#define NSTAGE 24       // 3 segments x 8 k-chunks of 32
#define OTM 128         // tokens per output block

// fp32 gap below which the top-2 go to fp64 refinement (bf16x3 dot err ~1e-2 bound)
#define REFINE_EPS 0.125f
// fp64 gap below which the reference's fp32 pipeline likely collapsed the two
// distances onto the same fp32 grid point -> first-occurrence -> LOWER index.
#define TIE_THETA 1.0e-4

// ws layout (floats):
//   [0]                    loss accum
//   [16 .. 16+1024)        c_sq (numpy-pairwise-exact)
//   [2048 .. +65536)       (unused; kept for layout stability)
//   [67584 .. +8*4*65536)  pairs (float4, chunk-major: pairs[c*N_TOK + t])
//   [then]                 cb packed tile-major bf16 hi/lo (1 MB)
#define WS_CSQ_OFF   16
#define WS_IDX_OFF   2048
#define WS_PAIRS_OFF (WS_IDX_OFF + N_TOK)
#define WS_CBPK_OFF  (WS_PAIRS_OFF + N_TOK * NCHUNK * 4)

typedef float f32x4  __attribute__((ext_vector_type(4)));
typedef short bf16x8 __attribute__((ext_vector_type(8)));
typedef short s16x8  __attribute__((ext_vector_type(8)));

// numpy-pairwise-exact row sum-of-squares for [rows, 256] fp32 (codebook).
// Also zeroes the loss accumulator (folded zero_loss launch).
__global__ void rowsq_np_kernel(const float* __restrict__ m,
                                float* __restrict__ out,
                                float* __restrict__ loss_ws, int rows) {
#pragma clang fp contract(off)
    if (blockIdx.x == 0 && threadIdx.x == 0) loss_ws[0] = 0.0f;
    int row = blockIdx.x * 16 + (threadIdx.x >> 4);
    int l   = threadIdx.x & 15;
    if (row >= rows) return;
    int h = l >> 3;
    int j = l & 7;
    const float* p = m + (size_t)row * DIM + h * 128 + j;
    float v = p[0];
    float r = v * v;
#pragma unroll
    for (int i = 1; i < 16; ++i) {
        float w  = p[i * 8];
        float w2 = w * w;
        r = r + w2;
    }
    float t = r + __shfl_xor(r, 1);
    t = t + __shfl_xor(t, 2);
    t = t + __shfl_xor(t, 4);
    t = t + __shfl_xor(t, 8);
    if (l == 0) out[row] = t;
}

// Insert (d, idx) into a sorted top-2 with lower-index tie-break.
__device__ __forceinline__ void ins2(float d, int idx,
                                     float& d1, int& i1, float& d2, int& i2) {
    if (d < d1 || (d == d1 && idx < i1)) {
        d2 = d1; i2 = i1; d1 = d; i1 = idx;
    } else if ((d < d2 || (d == d2 && idx < i2)) && idx != i1) {
        d2 = d; i2 = idx;
    }
}

// RNE fp32 -> bf16 split: v = hi + lo with lo capturing the residual.
__device__ __forceinline__ void f2bf_split(float v, short& hi, short& lo) {
    unsigned u = __float_as_uint(v);
    unsigned r = (u + 0x7fffu + ((u >> 16) & 1u)) >> 16;
    hi = (short)r;
    float hf = __uint_as_float(r << 16);
    float lf = v - hf;
    unsigned u2 = __float_as_uint(lf);
    unsigned r2 = (u2 + 0x7fffu + ((u2 >> 16) & 1u)) >> 16;
    lo = (short)r2;
}

// Tile-major pack (verbatim from the verified R2 kernel). Output: chunk
// c = (g*16 + part*8 + kc), each chunk 128 rows x 32 shorts (8 KB
// contiguous). Within a row, slot s (8 shorts) holds k-octet s^((r>>1)&3)
// of k-range [kc*32, kc*32+32) — the LDS bank swizzle baked into global
// layout so global_load_lds stages linearly on BOTH sides (rule #21) and
// ds_read uses slot = q ^ ((r>>1)&3).
__global__ void pack_tiles_kernel(const float* __restrict__ src,
                                  unsigned short* __restrict__ dst,
                                  int total) {       // total = rows * 32
    int tid = blockIdx.x * blockDim.x + threadIdx.x;
    if (tid >= total) return;
    int s   = tid & 3;
    int r   = (tid >> 2) & 127;
    int kc  = (tid >> 9) & 7;
    int g   = tid >> 12;
    int oct = s ^ ((r >> 1) & 3);

    const float4* xr = reinterpret_cast<const float4*>(
        src + ((size_t)(g * 128 + r)) * DIM + kc * 32 + oct * 8);
    float4 v0 = xr[0];
    float4 v1 = xr[1];

    float f[8] = {v0.x, v0.y, v0.z, v0.w, v1.x, v1.y, v1.z, v1.w};
    s16x8 hv, lv;
#pragma unroll
    for (int i = 0; i < 8; ++i) {
        short h, l;
        f2bf_split(f[i], h, l);
        hv[i] = h; lv[i] = l;
    }
    size_t base_hi = (((size_t)(g * 16 + kc) * 128 + r) << 5) + s * 8;
    size_t base_lo = (((size_t)(g * 16 + 8 + kc) * 128 + r) << 5) + s * 8;
    *reinterpret_cast<s16x8*>(dst + base_hi) = hv;
    *reinterpret_cast<s16x8*>(dst + base_lo) = lv;
}

// Async global -> LDS, 16 B per lane; LDS dest = uniform base + lane*16.
__device__ __forceinline__ void gload_lds16(const unsigned short* g, unsigned short* lds) {
    __builtin_amdgcn_global_load_lds(
        (const __attribute__((address_space(1))) unsigned int*)g,
        (__attribute__((address_space(3))) unsigned int*)lds, 16, 0, 0);
}

// MFMA distance + top-2. dist' = c_sq - 2*(x.c); ||x||^2 dropped (cancels).
// dot = hi*hi + hi*lo + lo*hi as one K=768 concat-GEMM over 3 segments.
//
// R6 = R2 (best verified, 646 us) + counted-vmcnt pipeline (m218 lever):
//  - Triple-buffered LDS (3 x 16 KB). Depth-2 prefetch: at stage s, stages
//    s and s+1 are in flight (8 loads/wave).
//  - Raw s_barrier + inline 's_waitcnt vmcnt(4)': wait ONLY for stage-s's
//    4 loads; stage s+1's stay in flight ACROSS the barrier. vmcnt never
//    drains to 0 inside the loop (drain-0 was R2's ~2x stall).
//  - Buffer-reuse proof: stage(s+2) targets buf (s+2)%3 == (s-1)%3, read at
//    iter s-1. Every wave's compute(s-1) (and its ds_reads, forced complete
//    by the lgkmcnt before MFMA) precedes its arrival at barrier(s), so at
//    barrier(s) that buffer is dead. One barrier per stage.
//  - setprio(1) around the 16-MFMA cluster (T5).
//  - Pack layout, stage copy, ds_read swizzle, accumulation order (seg-major,
//    kc ascending) verbatim from R2 -> bit-exact results.
__launch_bounds__(NTHREADS, 3)
__global__ void vq_main_kernel(const unsigned short* __restrict__ xpk,
                               const unsigned short* __restrict__ cbpk,
                               const float* __restrict__ csq,
                               float4* __restrict__ pairs) {
    // 3 x [ A: 128*32 | B: 128*32 ] shorts = 48 KB + 4 KB epilogue
    __shared__ __align__(16) unsigned short shbuf[3][2 * TM * BK];
    __shared__ float4 pairs_sh[TM][2];

    const int tid  = threadIdx.x;
    const int w    = tid >> 6;       // wave 0..3
    const int wy   = w >> 1;         // wave row (token dim)
    const int wx   = w & 1;          // wave col (code dim)
    const int lane = tid & 63;
    const int lm   = lane & 15;
    const int q    = lane >> 4;

    // XCD-grouped swizzle (bijective; inert on a 1-XCD partition, also
    // orders the 8 sibling chunk-blocks adjacently for L2 temporal reuse).
    const int bx     = blockIdx.x;
    const int jj     = bx >> 3;
    const int grp    = (bx & 7) + ((jj >> 3) << 3);
    const int cchunk = jj & 7;
    const int tok0   = grp * TM;
    const int code0  = cchunk * TN;

    float cs_reg[4];
#pragma unroll
    for (int ni = 0; ni < 4; ++ni)
        cs_reg[ni] = csq[code0 + wx * 64 + ni * 16 + lm];

    f32x4 acc[4][4];
#pragma unroll
    for (int mi = 0; mi < 4; ++mi)
#pragma unroll
        for (int ni = 0; ni < 4; ++ni)
            acc[mi][ni] = (f32x4){0.f, 0.f, 0.f, 0.f};

    // Loop-invariant fragment offsets (shorts): row r, k-octet q at
    // swizzled slot (q ^ ((r>>1)&3)).
    int offA[4], offB[4];
#pragma unroll
    for (int mi = 0; mi < 4; ++mi) {
        int r = wy * 64 + mi * 16 + lm;
        offA[mi] = r * BK + ((q ^ ((r >> 1) & 3)) * 8);
    }
#pragma unroll
    for (int ni = 0; ni < 4; ++ni) {
        int r = wx * 64 + ni * 16 + lm;
        offB[ni] = TM * BK + r * BK + ((q ^ ((r >> 1) & 3)) * 8);
    }

    // stage s (0..23): seg = s>>3, kc = s&7. A part: hi,hi,lo; B: hi,lo,hi.
    const int lsrc = w * 1024 + lane * 8;   // per-lane source offset (shorts)
    auto stage = [&](int p, int s) {
        const int seg = s >> 3;
        const int kc  = s & 7;
        const int pa  = (seg == 2) ? 8 : 0;
        const int pb  = (seg == 1) ? 8 : 0;
        const unsigned short* ga = xpk  + (((size_t)(grp    * 16 + pa + kc)) << 12) + lsrc;
        const unsigned short* gb = cbpk + (((size_t)(cchunk * 16 + pb + kc)) << 12) + lsrc;
        unsigned short* At = &shbuf[p][w * 1024];
        unsigned short* Bt = &shbuf[p][TM * BK + w * 1024];
        gload_lds16(ga,       At);
        gload_lds16(ga + 512, At + 512);
        gload_lds16(gb,       Bt);
        gload_lds16(gb + 512, Bt + 512);
    };

    // Prologue: 2 stages in flight (8 outstanding loads per wave).
    stage(0, 0);
    stage(1, 1);

    int pc = 0;                       // s % 3
#pragma unroll 1
    for (int s = 0; s < NSTAGE - 1; ++s) {
        // My stage-s 4 loads landed; stage-(s+1)'s 4 remain in flight.
        asm volatile("s_waitcnt vmcnt(4)" ::: "memory");
        __builtin_amdgcn_s_barrier();         // all waves' stage-s landed
        __builtin_amdgcn_sched_barrier(0);

        if (s + 2 < NSTAGE) {
            int pn = pc + 2; if (pn >= 3) pn -= 3;
            stage(pn, s + 2);                 // refill buffer freed at s-1
        }

        const unsigned short* buf = &shbuf[pc][0];
        bf16x8 af[4], bf[4];
#pragma unroll
        for (int mi = 0; mi < 4; ++mi)
            af[mi] = *reinterpret_cast<const bf16x8*>(buf + offA[mi]);
#pragma unroll
        for (int ni = 0; ni < 4; ++ni)
            bf[ni] = *reinterpret_cast<const bf16x8*>(buf + offB[ni]);

        __builtin_amdgcn_s_setprio(1);
#pragma unroll
        for (int mi = 0; mi < 4; ++mi)
#pragma unroll
            for (int ni = 0; ni < 4; ++ni)
                acc[mi][ni] = __builtin_amdgcn_mfma_f32_16x16x32_bf16(
                    af[mi], bf[ni], acc[mi][ni], 0, 0, 0);
        __builtin_amdgcn_s_setprio(0);

        pc = (pc == 2) ? 0 : pc + 1;
    }

    // Peeled last stage: only now drain to 0.
    asm volatile("s_waitcnt vmcnt(0)" ::: "memory");
    __builtin_amdgcn_s_barrier();
    __builtin_amdgcn_sched_barrier(0);
    {
        const unsigned short* buf = &shbuf[pc][0];
        bf16x8 af[4], bf[4];
#pragma unroll
        for (int mi = 0; mi < 4; ++mi)
            af[mi] = *reinterpret_cast<const bf16x8*>(buf + offA[mi]);
#pragma unroll
        for (int ni = 0; ni < 4; ++ni)
            bf[ni] = *reinterpret_cast<const bf16x8*>(buf + offB[ni]);
        __builtin_amdgcn_s_setprio(1);
#pragma unroll
        for (int mi = 0; mi < 4; ++mi)
#pragma unroll
            for (int ni = 0; ni < 4; ++ni)
                acc[mi][ni] = __builtin_amdgcn_mfma_f32_16x16x32_bf16(
                    af[mi], bf[ni], acc[mi][ni], 0, 0, 0);
        __builtin_amdgcn_s_setprio(0);
    }

    // Extraction: C/D layout row=(q*4+reg), col=lm per 16x16 tile (verified R6).
#pragma unroll
    for (int mi = 0; mi < 4; ++mi) {
#pragma unroll
        for (int r = 0; r < 4; ++r) {
            int row_local = wy * 64 + mi * 16 + q * 4 + r;
            float l1 = 3.4e38f, l2 = 3.4e38f;
            int   j1 = 0x7fffffff, j2 = 0x7fffffff;
#pragma unroll
            for (int ni = 0; ni < 4; ++ni) {
                float d = cs_reg[ni] - 2.0f * acc[mi][ni][r];
                ins2(d, code0 + wx * 64 + ni * 16 + lm, l1, j1, l2, j2);
            }
#pragma unroll
            for (int m = 1; m < 16; m <<= 1) {
                float o1 = __shfl_xor(l1, m);
                int   p1 = __shfl_xor(j1, m);
                float o2 = __shfl_xor(l2, m);
                int   p2 = __shfl_xor(j2, m);
                ins2(o1, p1, l1, j1, l2, j2);
                ins2(o2, p2, l1, j1, l2, j2);
            }
            if (lm == 0) {
                float4 pr;
                pr.x = l1; pr.y = l2;
                pr.z = __int_as_float(j1); pr.w = __int_as_float(j2);
                pairs_sh[row_local][wx] = pr;
            }
        }
    }
    __syncthreads();
    if (tid < TM) {
        float4 pa = pairs_sh[tid][0];
        float4 pb = pairs_sh[tid][1];
        float d1 = pa.x, d2 = pa.y;
        int   i1 = __float_as_int(pa.z), i2 = __float_as_int(pa.w);
        ins2(pb.x, __float_as_int(pb.z), d1, i1, d2, i2);
        ins2(pb.y, __float_as_int(pb.w), d1, i1, d2, i2);
        float4 pr;
        pr.x = d1; pr.y = d2;
        pr.z = __int_as_float(i1); pr.w = __int_as_float(i2);
        // chunk-major: contiguous 16B stores across tid
        pairs[(size_t)cchunk * N_TOK + tok0 + tid] = pr;
    }
}

// Fused merge + refine + output (was two kernels). Phase 1: 128 threads
// merge the 8 chunk top-2 pairs (ascending chunk order — identical ins2
// sequence to the verified merge) and fp64-refine near-ties. Phase 2: all
// 256 threads write quantized rows + indices + loss partials (identical
// math/order to the verified output_kernel).
__launch_bounds__(256)
__global__ void merge_output_kernel(const float* __restrict__ x,
                                    const float* __restrict__ cb,
                                    const float4* __restrict__ pairs,
                                    float* __restrict__ out_q,
                                    float* __restrict__ out_idx,
                                    float* __restrict__ loss_ws) {
    __shared__ int   sh_idx[OTM];
    __shared__ float wsum[4];
    const int tid  = threadIdx.x;
    const int tok0 = blockIdx.x * OTM;

    if (tid < OTM) {
        const int t = tok0 + tid;
        float4 p0 = pairs[t];
        float d1 = p0.x, d2 = p0.y;
        int   i1 = __float_as_int(p0.z), i2 = __float_as_int(p0.w);
#pragma unroll
        for (int c = 1; c < NCHUNK; ++c) {
            float4 p = pairs[(size_t)c * N_TOK + t];
            ins2(p.x, __float_as_int(p.z), d1, i1, d2, i2);
            ins2(p.y, __float_as_int(p.w), d1, i1, d2, i2);
        }

        int pick = i1;
        if (d2 - d1 < REFINE_EPS) {
            const float* xr = x + (size_t)t * DIM;
            const float* c1 = cb + (size_t)i1 * DIM;
            const float* c2 = cb + (size_t)i2 * DIM;
            double sA = 0.0, dA = 0.0, sB = 0.0, dB = 0.0;
            for (int k = 0; k < DIM; ++k) {
                double xv = (double)xr[k];
                double a  = (double)c1[k];
                double b  = (double)c2[k];
                sA += a * a; dA += xv * a;
                sB += b * b; dB += xv * b;
            }
            double DA  = sA - 2.0 * dA;
            double DB  = sB - 2.0 * dB;
            double gap = DB - DA;
            if (gap > TIE_THETA)       pick = i1;
            else if (gap < -TIE_THETA) pick = i2;
            else                       pick = (i1 < i2) ? i1 : i2;
        }
        sh_idx[tid] = pick;
        out_idx[t]  = (float)pick;
    }
    __syncthreads();

    float lsum = 0.0f;
    for (int t = 0; t < OTM; ++t) {
        int code = sh_idx[t];
        float qv = cb[(size_t)code * DIM + tid];
        float xv = x[(size_t)(tok0 + t) * DIM + tid];
        out_q[(size_t)(tok0 + t) * DIM + tid] = xv + (qv - xv);
        float df = xv - qv;
        lsum = fmaf(df, df, lsum);
    }

#pragma unroll
    for (int off = 1; off < 64; off <<= 1) lsum += __shfl_xor(lsum, off);
    if ((tid & 63) == 0) wsum[tid >> 6] = lsum;
    __syncthreads();
    if (tid == 0) atomicAdd(loss_ws, (wsum[0] + wsum[1]) + (wsum[2] + wsum[3]));
}

__global__ void finalize_kernel(const float* ws, float* out_loss) {
    if (threadIdx.x == 0) out_loss[0] = ws[0] * (1.0f / 16777216.0f); // COMMITMENT * mean
}

extern "C" void kernel_launch(void* const* d_in, const int* in_sizes, int n_in,
                              void* d_out, int out_size, void* d_ws, size_t ws_size,
                              hipStream_t stream) {
    const float* x  = (const float*)d_in[0];   // [16,4096,256] fp32
    const float* cb = (const float*)d_in[1];   // [1024,256] fp32

    float* out      = (float*)d_out;
    float* out_q    = out;
    float* out_idx  = out + (size_t)N_TOK * DIM;
    float* out_loss = out_idx + N_TOK;

    float*  ws    = (float*)d_ws;
    float*  csq   = ws + WS_CSQ_OFF;
    float4* pairs = (float4*)(ws + WS_PAIRS_OFF);
    unsigned short* cbpk = (unsigned short*)(ws + WS_CBPK_OFF);
    // x packed bf16 hi/lo lives in the out_q region (64 MB, overwritten later)
    unsigned short* xpk  = (unsigned short*)out_q;

    rowsq_np_kernel<<<KCODE / 16, 256, 0, stream>>>(cb, csq, ws, KCODE);
    // x: 65536 rows * 32 threads/row; cb: 1024 rows * 32 threads/row
    pack_tiles_kernel<<<(N_TOK * 32) / 256, 256, 0, stream>>>(x, xpk, N_TOK * 32);
    pack_tiles_kernel<<<(KCODE * 32) / 256, 256, 0, stream>>>(cb, cbpk, KCODE * 32);
    vq_main_kernel<<<(N_TOK / TM) * NCHUNK, NTHREADS, 0, stream>>>(xpk, cbpk, csq, pairs);
    merge_output_kernel<<<N_TOK / OTM, 256, 0, stream>>>(x, cb, pairs, out_q, out_idx, ws);
    finalize_kernel<<<1, 64, 0, stream>>>(ws, out_loss);
}